// Round 6
// baseline (496.991 us; speedup 1.0000x reference)
//
#include <hip/hip_runtime.h>

// GCN 2-layer inference: CSR gather w/ bf16 payload, packed (src,w) CSR entries,
// XCD-partitioned CSR build, non-temporal edge streaming (protects L2 dirty lines).
static constexpr int NPAD = 131072;
typedef unsigned int uint32;

__device__ __forceinline__ ushort f2bf(float f) {  // RNE f32->bf16
  uint32 u = __float_as_uint(f);
  return (ushort)((u + 0x7FFF + ((u >> 16) & 1)) >> 16);
}
__device__ __forceinline__ float bf_lo(uint32 u) { return __uint_as_float(u << 16); }
__device__ __forceinline__ float bf_hi(uint32 u) { return __uint_as_float(u & 0xFFFF0000u); }
__device__ __forceinline__ float bfu(ushort u) { return __uint_as_float((uint32)u << 16); }

// XCD-partitioned degree histogram; nt reads keep degi lines resident.
__global__ __launch_bounds__(256) void deg_kernel(const int* __restrict__ dst,
                                                  int* __restrict__ degi, int nE,
                                                  int nPerXcd) {
  const int xcd = blockIdx.x & 7;
  const int sub = blockIdx.x >> 3;
  const int nsub = gridDim.x >> 3;
  const int lo = xcd * nPerXcd, hi = lo + nPerXcd;
  for (int i = sub * 256 + threadIdx.x; i < nE; i += nsub * 256) {
    int d = __builtin_nontemporal_load(&dst[i]);
    if (d >= lo && d < hi) atomicAdd(&degi[d], 1);
  }
}

__global__ __launch_bounds__(256) void dis_kernel(const int* __restrict__ degi,
                                                  float* __restrict__ dis, int n) {
  int i = blockIdx.x * 256 + threadIdx.x;
  if (i < n) dis[i] = rsqrtf((float)degi[i] + 1.0f);  // +1 = self loop
}

__global__ __launch_bounds__(256) void block_sum_kernel(const int* __restrict__ degi,
                                                        int* __restrict__ bsum, int n) {
  __shared__ int sm[256];
  int i = blockIdx.x * 256 + threadIdx.x;
  sm[threadIdx.x] = (i < n) ? degi[i] : 0;
  __syncthreads();
  for (int s = 128; s > 0; s >>= 1) {
    if (threadIdx.x < s) sm[threadIdx.x] += sm[threadIdx.x + s];
    __syncthreads();
  }
  if (threadIdx.x == 0) bsum[blockIdx.x] = sm[0];
}

__global__ __launch_bounds__(512) void scan_bsum_kernel(int* __restrict__ bsum, int nb) {
  __shared__ int sm[512];
  int v = (threadIdx.x < nb) ? bsum[threadIdx.x] : 0;
  sm[threadIdx.x] = v;
  __syncthreads();
  for (int off = 1; off < 512; off <<= 1) {
    int t = (threadIdx.x >= off) ? sm[threadIdx.x - off] : 0;
    __syncthreads();
    sm[threadIdx.x] += t;
    __syncthreads();
  }
  if (threadIdx.x < nb) bsum[threadIdx.x] = sm[threadIdx.x] - v;  // exclusive
}

__global__ __launch_bounds__(256) void scan_local_kernel(const int* __restrict__ degi,
                                                         const int* __restrict__ bsum,
                                                         int* __restrict__ row_start,
                                                         int* __restrict__ cursor, int n) {
  __shared__ int sm[256];
  int i = blockIdx.x * 256 + threadIdx.x;
  int v = (i < n) ? degi[i] : 0;
  sm[threadIdx.x] = v;
  __syncthreads();
  for (int off = 1; off < 256; off <<= 1) {
    int t = (threadIdx.x >= off) ? sm[threadIdx.x - off] : 0;
    __syncthreads();
    sm[threadIdx.x] += t;
    __syncthreads();
  }
  int excl = sm[threadIdx.x] - v + bsum[blockIdx.x];
  if (i < n) { row_start[i] = excl; cursor[i] = excl; }
  if (i == n - 1) row_start[n] = excl + v;  // = E
}

// XCD-partitioned CSR fill; nt edge reads so the 1.6MB dirty slice stays in L2.
__global__ __launch_bounds__(256) void fill_csr_kernel(const int* __restrict__ src,
                                                       const int* __restrict__ dst,
                                                       const float* __restrict__ dis,
                                                       int* __restrict__ cursor,
                                                       uint2* __restrict__ csr_pack,
                                                       int nE, int nPerXcd) {
  const int xcd = blockIdx.x & 7;
  const int sub = blockIdx.x >> 3;
  const int nsub = gridDim.x >> 3;
  const int lo = xcd * nPerXcd, hi = lo + nPerXcd;
  for (int i = sub * 256 + threadIdx.x; i < nE; i += nsub * 256) {
    int d = __builtin_nontemporal_load(&dst[i]);
    if (d >= lo && d < hi) {
      int s = __builtin_nontemporal_load(&src[i]);
      int pos = atomicAdd(&cursor[d], 1);
      csr_pack[pos] = make_uint2((uint32)s, __float_as_uint(dis[s] * dis[d]));
    }
  }
}

// H_bf16[128rows x COLS] = (relu?)X[128rows x 128] @ W[128 x COLS]; X fp32 or bf16.
template <int COLS, bool RELU_IN, bool IN_BF16>
__global__ __launch_bounds__(256) void gemm_kernel(const void* __restrict__ Xv,
                                                   const float* __restrict__ W,
                                                   ushort* __restrict__ H, int n) {
  constexpr int KC = 32;
  constexpr int RT = 132;
  constexpr int TN = (COLS == 128) ? 8 : 4;
  __shared__ float sX[KC][RT];
  __shared__ float sW[KC][COLS];
  const int t = threadIdx.x;
  const int row0 = blockIdx.x * 128;
  const int r0 = (t >> 4) * 8;
  const int c0 = (t & 15) * 4;

  float acc[8][TN];
#pragma unroll
  for (int i = 0; i < 8; ++i)
#pragma unroll
    for (int j = 0; j < TN; ++j) acc[i][j] = 0.f;

  for (int k0 = 0; k0 < 128; k0 += KC) {
#pragma unroll
    for (int p = 0; p < 4; ++p) {
      int idx = p * 256 + t;
      int r = idx >> 3;
      int f = idx & 7;
      int gr = row0 + r;
      float4 v = make_float4(0.f, 0.f, 0.f, 0.f);
      if (gr < n) {
        if (IN_BF16) {
          const ushort* Xb = (const ushort*)Xv;
          ushort4 uv = *(const ushort4*)(Xb + (size_t)gr * 128 + k0 + f * 4);
          v = make_float4(bfu(uv.x), bfu(uv.y), bfu(uv.z), bfu(uv.w));
        } else {
          v = *(const float4*)((const float*)Xv + (size_t)gr * 128 + k0 + f * 4);
        }
      }
      if (RELU_IN) {
        v.x = fmaxf(v.x, 0.f); v.y = fmaxf(v.y, 0.f);
        v.z = fmaxf(v.z, 0.f); v.w = fmaxf(v.w, 0.f);
      }
      int kk = f * 4;
      sX[kk + 0][r] = v.x; sX[kk + 1][r] = v.y;
      sX[kk + 2][r] = v.z; sX[kk + 3][r] = v.w;
    }
    constexpr int WP = (KC * COLS) / (256 * 4);
#pragma unroll
    for (int p = 0; p < WP; ++p) {
      int idx = p * 256 + t;
      int k = idx / (COLS / 4);
      int c4 = idx % (COLS / 4);
      *(float4*)&sW[k][c4 * 4] = *(const float4*)(W + (size_t)(k0 + k) * COLS + c4 * 4);
    }
    __syncthreads();
#pragma unroll 8
    for (int k = 0; k < KC; ++k) {
      float4 xa = *(const float4*)&sX[k][r0];
      float4 xb = *(const float4*)&sX[k][r0 + 4];
      float4 wa = *(const float4*)&sW[k][c0];
      float xr[8] = {xa.x, xa.y, xa.z, xa.w, xb.x, xb.y, xb.z, xb.w};
      if (COLS == 128) {
        float4 wb = *(const float4*)&sW[k][c0 + 64];
        float wr[8] = {wa.x, wa.y, wa.z, wa.w, wb.x, wb.y, wb.z, wb.w};
#pragma unroll
        for (int i = 0; i < 8; ++i)
#pragma unroll
          for (int j = 0; j < 8; ++j) acc[i][j] = fmaf(xr[i], wr[j], acc[i][j]);
      } else {
        float wr[4] = {wa.x, wa.y, wa.z, wa.w};
#pragma unroll
        for (int i = 0; i < 8; ++i)
#pragma unroll
          for (int j = 0; j < 4; ++j) acc[i][j] = fmaf(xr[i], wr[j], acc[i][j]);
      }
    }
    __syncthreads();
  }
#pragma unroll
  for (int i = 0; i < 8; ++i) {
    int row = row0 + r0 + i;
    if (row >= n) break;
    ushort* hrow = H + (size_t)row * COLS;
    ushort4 s0;
    s0.x = f2bf(acc[i][0]); s0.y = f2bf(acc[i][1]);
    s0.z = f2bf(acc[i][2]); s0.w = f2bf(acc[i][3]);
    *(ushort4*)&hrow[c0] = s0;
    if (COLS == 128) {
      ushort4 s1;
      s1.x = f2bf(acc[i][4]); s1.y = f2bf(acc[i][5]);
      s1.z = f2bf(acc[i][6]); s1.w = f2bf(acc[i][7]);
      *(ushort4*)&hrow[c0 + 64] = s1;
    }
  }
}

// One wave per dst node: out[d] = sum_e w_e*h[s_e] + dis[d]^2*h[d] + b  (h bf16).
// csr = packed pairs (src, weight_bits), streamed nt. OUT_BF16: pack 2 bf16/lane.
template <int COLS, bool OUT_BF16>
__global__ __launch_bounds__(256) void agg_kernel(const int* __restrict__ row_start,
                                                  const uint32* __restrict__ csr,
                                                  const float* __restrict__ dis,
                                                  const ushort* __restrict__ h,
                                                  const float* __restrict__ bias,
                                                  void* __restrict__ outv, int n) {
  const int lane = threadIdx.x & 63;
  int wv = blockIdx.x * 4 + (threadIdx.x >> 6);
  const int nwv = gridDim.x * 4;
  for (int d = wv; d < n; d += nwv) {
    const int e0 = row_start[d], e1 = row_start[d + 1];
    const float dd = dis[d];
    if (COLS == 128) {
      uint32 hv = ((const uint32*)(h + (size_t)d * 128))[lane];
      float sq = dd * dd;
      float acx = sq * bf_lo(hv), acy = sq * bf_hi(hv);
      int e = e0;
      for (; e + 7 < e1; e += 8) {
        uint32 s[8], wb[8], a[8];
#pragma unroll
        for (int j = 0; j < 8; ++j) {
          s[j]  = __builtin_nontemporal_load(&csr[2 * (e + j)]);
          wb[j] = __builtin_nontemporal_load(&csr[2 * (e + j) + 1]);
        }
#pragma unroll
        for (int j = 0; j < 8; ++j) a[j] = ((const uint32*)(h + (size_t)s[j] * 128))[lane];
#pragma unroll
        for (int j = 0; j < 8; ++j) {
          float w = __uint_as_float(wb[j]);
          acx = fmaf(w, bf_lo(a[j]), acx); acy = fmaf(w, bf_hi(a[j]), acy);
        }
      }
      for (; e + 3 < e1; e += 4) {
        uint32 s[4], wb[4], a[4];
#pragma unroll
        for (int j = 0; j < 4; ++j) {
          s[j]  = __builtin_nontemporal_load(&csr[2 * (e + j)]);
          wb[j] = __builtin_nontemporal_load(&csr[2 * (e + j) + 1]);
        }
#pragma unroll
        for (int j = 0; j < 4; ++j) a[j] = ((const uint32*)(h + (size_t)s[j] * 128))[lane];
#pragma unroll
        for (int j = 0; j < 4; ++j) {
          float w = __uint_as_float(wb[j]);
          acx = fmaf(w, bf_lo(a[j]), acx); acy = fmaf(w, bf_hi(a[j]), acy);
        }
      }
      for (; e < e1; ++e) {
        uint32 s0 = csr[2 * e];
        float w0 = __uint_as_float(csr[2 * e + 1]);
        uint32 a0 = ((const uint32*)(h + (size_t)s0 * 128))[lane];
        acx = fmaf(w0, bf_lo(a0), acx); acy = fmaf(w0, bf_hi(a0), acy);
      }
      float2 bv = ((const float2*)bias)[lane];
      acx += bv.x; acy += bv.y;
      if (OUT_BF16) {
        uint32 pk = ((uint32)f2bf(acy) << 16) | (uint32)f2bf(acx);
        __builtin_nontemporal_store(pk, &((uint32*)outv)[(size_t)d * 64 + lane]);
      } else {
        float* o = (float*)outv + (size_t)d * 128 + 2 * lane;
        __builtin_nontemporal_store(acx, o);
        __builtin_nontemporal_store(acy, o + 1);
      }
    } else {
      float acc = dd * dd * bfu(h[(size_t)d * 64 + lane]);
      int e = e0;
      for (; e + 7 < e1; e += 8) {
        uint32 s[8], wb[8];
        float a[8];
#pragma unroll
        for (int j = 0; j < 8; ++j) {
          s[j]  = __builtin_nontemporal_load(&csr[2 * (e + j)]);
          wb[j] = __builtin_nontemporal_load(&csr[2 * (e + j) + 1]);
        }
#pragma unroll
        for (int j = 0; j < 8; ++j) a[j] = bfu(h[(size_t)s[j] * 64 + lane]);
#pragma unroll
        for (int j = 0; j < 8; ++j) acc = fmaf(__uint_as_float(wb[j]), a[j], acc);
      }
      for (; e < e1; ++e)
        acc = fmaf(__uint_as_float(csr[2 * e + 1]), bfu(h[(size_t)csr[2 * e] * 64 + lane]), acc);
      float o = acc + bias[lane];
      __builtin_nontemporal_store(o, (float*)outv + (size_t)d * 64 + lane);
    }
  }
}

extern "C" void kernel_launch(void* const* d_in, const int* in_sizes, int n_in,
                              void* d_out, int out_size, void* d_ws, size_t ws_size,
                              hipStream_t stream) {
  const float* x  = (const float*)d_in[0];
  const int* ei   = (const int*)d_in[1];   // [2, E] int32
  const float* W1 = (const float*)d_in[2];
  const float* b1 = (const float*)d_in[3];
  const float* W2 = (const float*)d_in[4];
  const float* b2 = (const float*)d_in[5];
  float* out = (float*)d_out;

  const int N = in_sizes[0] / 128;  // 100000
  const int E = in_sizes[1] / 2;    // 1600000
  const int* srcI = ei;
  const int* dstI = ei + E;
  const int nPerXcd = (N + 7) / 8;

  char* w = (char*)d_ws;
  float* dis      = (float*)w;                 w += (size_t)NPAD * 4;
  int* degi       = (int*)w;                   w += (size_t)NPAD * 4;
  int* row_start  = (int*)w;                   w += (size_t)NPAD * 4;
  int* cursor     = (int*)w;                   w += (size_t)NPAD * 4;
  int* bsum       = (int*)w;                   w += 4096 * 4;
  uint2* csr_pack = (uint2*)w;                 w += (size_t)E * 8;
  ushort* h       = (ushort*)w;                w += (size_t)N * 128 * 2;  // bf16
  ushort* out1    = (ushort*)w;                w += (size_t)N * 128 * 2;  // bf16
  ushort* g       = h;  // layer-2 bf16 out aliases dead h

  const int nb = (N + 255) / 256;  // 391 <= 512

  // CSR build (deg + fill are XCD-partitioned by dst range, nt edge streams)
  hipMemsetAsync(degi, 0, (size_t)N * sizeof(int), stream);
  deg_kernel<<<2048, 256, 0, stream>>>(dstI, degi, E, nPerXcd);
  dis_kernel<<<(N + 255) / 256, 256, 0, stream>>>(degi, dis, N);
  block_sum_kernel<<<nb, 256, 0, stream>>>(degi, bsum, N);
  scan_bsum_kernel<<<1, 512, 0, stream>>>(bsum, nb);
  scan_local_kernel<<<nb, 256, 0, stream>>>(degi, bsum, row_start, cursor, N);
  fill_csr_kernel<<<2048, 256, 0, stream>>>(srcI, dstI, dis, cursor, csr_pack, E, nPerXcd);

  // layer 1
  gemm_kernel<128, false, false><<<(N + 127) / 128, 256, 0, stream>>>(x, W1, h, N);
  agg_kernel<128, true><<<2048, 256, 0, stream>>>(row_start, (const uint32*)csr_pack, dis, h, b1, out1, N);

  // layer 2 (relu fused into GEMM2 load, bf16 in)
  gemm_kernel<64, true, true><<<(N + 127) / 128, 256, 0, stream>>>(out1, W2, g, N);
  agg_kernel<64, false><<<2048, 256, 0, stream>>>(row_start, (const uint32*)csr_pack, dis, g, b2, out, N);
}